// Round 9
// baseline (971.069 us; speedup 1.0000x reference)
//
#include <hip/hip_runtime.h>
#include <cstdint>

#define NT 512

// ws float offsets
static constexpr int W0T_OFF = 0;        // w0T[gc][m]  : [2600][32] = 83200
static constexpr int W1T_OFF = 83200;    // w1T[k][o][28] : [50][52][28] = 72800 (26 used + 2 pad)
static constexpr int W2T_OFF = 156000;   // w2T[k][o][28] : 72800
static constexpr int CF_OFF  = 228800;   // gate coeffs float4 [3][1300] = 15600 floats
static constexpr int LG_OFF  = 244400;   // logits [B][10] f32

// ---------------------------------------------------------------------------
// Precompute: softmax conn weights (axis=1), stored per-column contiguous
// (w0T: 32/col; w1T/w2T: 26/col padded to 28 for 16B-aligned loads), and
// collapse the 16-gate bank to gate(A,B) = a + b*A + c*B + d*A*B.
// ---------------------------------------------------------------------------
__global__ void precompute_kernel(const float* __restrict__ c0,
                                  const float* __restrict__ w0,
                                  const float* __restrict__ c1,
                                  const float* __restrict__ w1,
                                  const float* __restrict__ c2,
                                  const float* __restrict__ w2,
                                  float* __restrict__ ws) {
  int id = blockIdx.x * blockDim.x + threadIdx.x;
  if (id < 2600) {  // layer-1 col gc=(n,o): softmax over m=32 (stride 325 in src)
    int n = id / 325, o = id - n * 325;
    const float* src = c0 + n * (32 * 325) + o;
    float v[32]; float mx = -3.4e38f;
#pragma unroll
    for (int m = 0; m < 32; ++m) { v[m] = src[m * 325]; mx = fmaxf(mx, v[m]); }
    float ssum = 0.f;
#pragma unroll
    for (int m = 0; m < 32; ++m) { v[m] = __expf(v[m] - mx); ssum += v[m]; }
    float inv = 1.f / ssum;
    float* dst = ws + W0T_OFF + (size_t)id * 32;
#pragma unroll
    for (int m = 0; m < 32; ++m) dst[m] = v[m] * inv;
    return;
  }
  id -= 2600;
  if (id < 5200) {  // layer-2/3 col (k,o): softmax over m=26
    const float* src0 = (id < 2600) ? c1 : c2;
    float* dst0 = ws + ((id < 2600) ? W1T_OFF : W2T_OFF);
    int col = (id < 2600) ? id : id - 2600;
    int k = col / 52, o = col - k * 52;
    const float* src = src0 + k * (26 * 52) + o;
    float v[26]; float mx = -3.4e38f;
#pragma unroll
    for (int m = 0; m < 26; ++m) { v[m] = src[m * 52]; mx = fmaxf(mx, v[m]); }
    float ssum = 0.f;
#pragma unroll
    for (int m = 0; m < 26; ++m) { v[m] = __expf(v[m] - mx); ssum += v[m]; }
    float inv = 1.f / ssum;
    float* dst = dst0 + (size_t)(k * 52 + o) * 28;
#pragma unroll
    for (int m = 0; m < 26; ++m) dst[m] = v[m] * inv;
    return;
  }
  id -= 5200;
  if (id < 3900) {  // gate coefficients
    int layer = id / 1300, g = id - layer * 1300;
    const float* w = (layer == 0) ? w0 : ((layer == 1) ? w1 : w2);
    float v[16]; float mx = -3.4e38f;
#pragma unroll
    for (int k = 0; k < 16; ++k) { v[k] = w[k * 1300 + g]; mx = fmaxf(mx, v[k]); }
    float ssum = 0.f;
#pragma unroll
    for (int k = 0; k < 16; ++k) { v[k] = __expf(v[k] - mx); ssum += v[k]; }
    float inv = 1.f / ssum;
#pragma unroll
    for (int k = 0; k < 16; ++k) v[k] *= inv;
    float alpha = v[8] + v[9] + v[10] + v[11] + v[12] + v[13] + v[14] + v[15];
    float beta  = v[2] + v[3] + v[6] + v[7] - v[8] - v[9] - v[12] - v[13];
    float gamma = v[4] + v[5] + v[6] + v[7] - v[8] - v[9] - v[10] - v[11];
    float delta = v[1] - v[2] - v[4] - 2.f * v[6] - v[7] + v[8] + 2.f * v[9]
                + v[11] + v[13] - v[14];
    reinterpret_cast<float4*>(ws + CF_OFF)[id] =
        make_float4(alpha, beta, gamma, delta);
  }
}

__device__ __forceinline__ float gate4(float4 cv, float a0, float a1) {
  return fmaf(cv.w, a0 * a1, fmaf(cv.z, a1, fmaf(cv.y, a0, cv.x)));
}
__device__ __forceinline__ float4 vload4(const float* p) {
  return *reinterpret_cast<const float4*>(p);
}

// ---------------------------------------------------------------------------
// Weight-stationary chain kernel.
// Grid = 256 tiles (64 samples) x 2 halves (chains 0-24 / 25-49) = 512 WGs
// = exactly 2 WGs/CU. WG = 8 waves; each wave owns 3-4 whole chains.
// Lane o in [0,52) owns output column o of the chain for ALL layers:
//   - weights: per-lane coalesced VMEM loads into registers, reused over
//     64 samples (pipelinable, unlike the old wave-uniform s_load path)
//   - x/h operand: broadcast ds_read_b128 from LDS (uniform addr, counted
//     by lgkmcnt -> deeply pipelinable)
//   - pair gating: __shfl_xor(1); even lane writes gated value
//   - h ping-pongs in per-wave LDS chunks of 16 samples; NO barriers in
//     the main loop (same-wave producer/consumer)
//   - layer-3: lane-per-sample column sum -> one LDS atomicAdd per sample
// ---------------------------------------------------------------------------
static constexpr int XBT_STRIDE = 68;             // 64 samples + 4 pad
static constexpr int XBT_FLOATS = 4 * 32 * XBT_STRIDE;  // 8704
static constexpr int HCH = 16;                    // chunk samples
static constexpr int HW_FLOATS = 26 * HCH;        // 416 per buffer
static constexpr int LG_FLOATS = 64 * 5;

__global__ __launch_bounds__(NT, 4) void chain_kernel(
    const float* __restrict__ x, const float* __restrict__ ws,
    float* __restrict__ lgout, int B) {
  extern __shared__ float smem[];
  float* xbt = smem;                              // [4][32][68]  ((n*32+j)*68+s)
  float* hwv = smem + XBT_FLOATS;                 // [8 waves][2][416]
  float* lgb = smem + XBT_FLOATS + 8 * 2 * HW_FLOATS;  // [64][5]
  const int tid = threadIdx.x;
  const int bid = blockIdx.x;
  const int tile = bid >> 1;
  const int half = bid & 1;
  const int s0 = tile * 64;

  // ---- stage x (transposed): this half's 128 input cols -> xbt ----
  {
    const float4* x4 = reinterpret_cast<const float4*>(x);
    for (int idx = tid; idx < 64 * 32; idx += NT) {
      int r = idx >> 5, c4 = idx & 31;
      float4 v = make_float4(0.f, 0.f, 0.f, 0.f);
      if (s0 + r < B) v = x4[(size_t)(s0 + r) * 64 + half * 32 + c4];
      int c = c4 * 4;  // within-half col; c..c+3 stay in one 32-block
      float* d = xbt + ((c >> 5) * 32 + (c & 31)) * XBT_STRIDE + r;
      d[0] = v.x; d[XBT_STRIDE] = v.y;
      d[2 * XBT_STRIDE] = v.z; d[3 * XBT_STRIDE] = v.w;
    }
    for (int i = tid; i < LG_FLOATS; i += NT) lgb[i] = 0.f;
  }
  __syncthreads();

  const int lane = tid & 63;
  const int wv = __builtin_amdgcn_readfirstlane(tid >> 6);  // 0..7
  float* ha = hwv + wv * (2 * HW_FLOATS);
  float* hb = ha + HW_FLOATS;
  const int o = lane;
  const bool act = (o < 52);
  const int oc = act ? o : 51;          // clamp for safe addressing
  const bool wri = act && ((o & 1) == 0);
  const int q = oc >> 1;                // local pair index 0..25
  const float* cfb = ws + CF_OFF;

  // chains per wave: wave 0 -> 4, waves 1..7 -> 3   (total 25)
  const int cw = (wv == 0) ? 4 : 3;
  const int cst = (wv == 0) ? 0 : 4 + 3 * (wv - 1);

#pragma unroll 1
  for (int ci = 0; ci < cw; ++ci) {
    const int K = half * 25 + cst + ci;
    const int gc = 52 * K + oc;                   // this lane's layer-1 col
    const int nrel = (int)((unsigned)gc / 325u) - half * 4;
    const float* xcol = xbt + nrel * (32 * XBT_STRIDE);
    const int cls = K / 5 - half * 5;

    // layer-1 weights: 32 floats/lane, resident across the whole chain
    float w1r[32];
    {
      const float* wp = ws + W0T_OFF + (size_t)gc * 32;
#pragma unroll
      for (int t = 0; t < 8; ++t) {
        float4 v = vload4(wp + 4 * t);
        w1r[4 * t] = v.x; w1r[4 * t + 1] = v.y;
        w1r[4 * t + 2] = v.z; w1r[4 * t + 3] = v.w;
      }
    }
    const float4 cf0 = vload4(cfb + (size_t)(26 * K + q) * 4);

#pragma unroll 1
    for (int ck = 0; ck < 4; ++ck) {
      const int sb = ck * HCH;

      // ---- layer 1: x (broadcast LDS) x w1r -> gate -> ha[26][16] ----
#pragma unroll
      for (int g = 0; g < 4; ++g) {
        float a0 = 0.f, a1 = 0.f, a2 = 0.f, a3 = 0.f;
        const float* xp = xcol + sb + g * 4;
#pragma unroll
        for (int j = 0; j < 32; ++j) {
          float4 xv = *reinterpret_cast<const float4*>(xp + j * XBT_STRIDE);
          a0 = fmaf(w1r[j], xv.x, a0);
          a1 = fmaf(w1r[j], xv.y, a1);
          a2 = fmaf(w1r[j], xv.z, a2);
          a3 = fmaf(w1r[j], xv.w, a3);
        }
        float p0 = __shfl_xor(a0, 1), p1 = __shfl_xor(a1, 1);
        float p2 = __shfl_xor(a2, 1), p3 = __shfl_xor(a3, 1);
        if (wri) {
          float4 gv = make_float4(gate4(cf0, a0, p0), gate4(cf0, a1, p1),
                                  gate4(cf0, a2, p2), gate4(cf0, a3, p3));
          *reinterpret_cast<float4*>(ha + q * HCH + g * 4) = gv;
        }
      }

      // ---- layer 2: ha (broadcast) x w2r -> gate -> hb ----
      {
        const float* wp = ws + W1T_OFF + ((size_t)K * 52 + oc) * 28;
        const float4 cf1 = vload4(cfb + (size_t)(1300 + 26 * K + q) * 4);
        float w2r[26];
#pragma unroll
        for (int t = 0; t < 7; ++t) {
          float4 v = vload4(wp + 4 * t);
          if (4 * t + 0 < 26) w2r[4 * t + 0] = v.x;
          if (4 * t + 1 < 26) w2r[4 * t + 1] = v.y;
          if (4 * t + 2 < 26) w2r[4 * t + 2] = v.z;
          if (4 * t + 3 < 26) w2r[4 * t + 3] = v.w;
        }
#pragma unroll
        for (int g = 0; g < 4; ++g) {
          float a0 = 0.f, a1 = 0.f, a2 = 0.f, a3 = 0.f;
#pragma unroll
          for (int j = 0; j < 26; ++j) {
            float4 hv = *reinterpret_cast<const float4*>(ha + j * HCH + g * 4);
            a0 = fmaf(w2r[j], hv.x, a0);
            a1 = fmaf(w2r[j], hv.y, a1);
            a2 = fmaf(w2r[j], hv.z, a2);
            a3 = fmaf(w2r[j], hv.w, a3);
          }
          float p0 = __shfl_xor(a0, 1), p1 = __shfl_xor(a1, 1);
          float p2 = __shfl_xor(a2, 1), p3 = __shfl_xor(a3, 1);
          if (wri) {
            float4 gv = make_float4(gate4(cf1, a0, p0), gate4(cf1, a1, p1),
                                    gate4(cf1, a2, p2), gate4(cf1, a3, p3));
            *reinterpret_cast<float4*>(hb + q * HCH + g * 4) = gv;
          }
        }
      }

      // ---- layer 3: hb (broadcast) x w3r -> gate -> ha (reuse) ----
      {
        const float* wp = ws + W2T_OFF + ((size_t)K * 52 + oc) * 28;
        const float4 cf2 = vload4(cfb + (size_t)(2600 + 26 * K + q) * 4);
        float w3r[26];
#pragma unroll
        for (int t = 0; t < 7; ++t) {
          float4 v = vload4(wp + 4 * t);
          if (4 * t + 0 < 26) w3r[4 * t + 0] = v.x;
          if (4 * t + 1 < 26) w3r[4 * t + 1] = v.y;
          if (4 * t + 2 < 26) w3r[4 * t + 2] = v.z;
          if (4 * t + 3 < 26) w3r[4 * t + 3] = v.w;
        }
#pragma unroll
        for (int g = 0; g < 4; ++g) {
          float a0 = 0.f, a1 = 0.f, a2 = 0.f, a3 = 0.f;
#pragma unroll
          for (int j = 0; j < 26; ++j) {
            float4 hv = *reinterpret_cast<const float4*>(hb + j * HCH + g * 4);
            a0 = fmaf(w3r[j], hv.x, a0);
            a1 = fmaf(w3r[j], hv.y, a1);
            a2 = fmaf(w3r[j], hv.z, a2);
            a3 = fmaf(w3r[j], hv.w, a3);
          }
          float p0 = __shfl_xor(a0, 1), p1 = __shfl_xor(a1, 1);
          float p2 = __shfl_xor(a2, 1), p3 = __shfl_xor(a3, 1);
          if (wri) {
            float4 gv = make_float4(gate4(cf2, a0, p0), gate4(cf2, a1, p1),
                                    gate4(cf2, a2, p2), gate4(cf2, a3, p3));
            *reinterpret_cast<float4*>(ha + q * HCH + g * 4) = gv;
          }
        }
      }

      // ---- chunk reduce: lane = sample, sum 26 gated values ----
      if (lane < HCH) {
        float tot = 0.f;
#pragma unroll
        for (int j = 0; j < 26; ++j) tot += ha[j * HCH + lane];
        atomicAdd(&lgb[(sb + lane) * 5 + cls], tot);
      }
    }
  }
  __syncthreads();

  // ---- write this half's 5 classes (disjoint across WGs) ----
  for (int i = tid; i < LG_FLOATS; i += NT) {
    int s = i / 5, c = i - (i / 5) * 5;
    if (s0 + s < B) lgout[(size_t)(s0 + s) * 10 + half * 5 + c] = lgb[i];
  }
}

// ---------------------------------------------------------------------------
// Finalize: per-sample 10-way softmax.
// ---------------------------------------------------------------------------
__global__ __launch_bounds__(256) void softmax_kernel(
    const float* __restrict__ lgin, float* __restrict__ out, int B) {
  int s = blockIdx.x * 256 + threadIdx.x;
  if (s >= B) return;
  float lg[10];
#pragma unroll
  for (int c = 0; c < 10; ++c) lg[c] = lgin[(size_t)s * 10 + c];
  float mx = lg[0];
#pragma unroll
  for (int c = 1; c < 10; ++c) mx = fmaxf(mx, lg[c]);
  float ssum = 0.f;
#pragma unroll
  for (int c = 0; c < 10; ++c) { lg[c] = __expf(lg[c] - mx); ssum += lg[c]; }
  float inv = 1.f / ssum;
  float* o = out + (size_t)s * 10;
#pragma unroll
  for (int c = 0; c < 10; ++c) o[c] = lg[c] * inv;
}

extern "C" void kernel_launch(void* const* d_in, const int* in_sizes, int n_in,
                              void* d_out, int out_size, void* d_ws, size_t ws_size,
                              hipStream_t stream) {
  const float* x  = (const float*)d_in[0];
  const float* c0 = (const float*)d_in[1];
  const float* w0 = (const float*)d_in[2];
  const float* c1 = (const float*)d_in[3];
  const float* w1 = (const float*)d_in[4];
  const float* c2 = (const float*)d_in[5];
  const float* w2 = (const float*)d_in[6];
  float* out = (float*)d_out;
  float* ws  = (float*)d_ws;
  const int B = in_sizes[0] / 256;

  precompute_kernel<<<46, 256, 0, stream>>>(c0, w0, c1, w1, c2, w2, ws);

  const size_t smem_bytes =
      (size_t)(XBT_FLOATS + 8 * 2 * HW_FLOATS + LG_FLOATS) * sizeof(float);
  hipFuncSetAttribute(reinterpret_cast<const void*>(chain_kernel),
                      hipFuncAttributeMaxDynamicSharedMemorySize, (int)smem_bytes);
  const int nblk = (B + 63) / 64;
  chain_kernel<<<nblk * 2, NT, smem_bytes, stream>>>(x, ws, ws + LG_OFF, B);
  softmax_kernel<<<(B + 255) / 256, 256, 0, stream>>>(ws + LG_OFF, out, B);
}

// Round 10
// 230.732 us; speedup vs baseline: 4.2087x; 4.2087x over previous
//
#include <hip/hip_runtime.h>
#include <cstdint>

#define NT 512

// ws float offsets
static constexpr int W0T_OFF = 0;        // w0T[gc][32] : [2600][32] = 83200
static constexpr int W1T_OFF = 83200;    // w1T[k][o][28] : [50][52][28] = 72800
static constexpr int W2T_OFF = 156000;   // w2T[k][o][28] : 72800
static constexpr int CF_OFF  = 228800;   // gate coeffs float4 [3][1300] = 15600 floats
static constexpr int LG_OFF  = 244400;   // logits [B][10] f32

// ---------------------------------------------------------------------------
// Precompute: softmax conn weights (axis=1) stored per-column contiguous,
// collapse 16-gate bank to gate(A,B) = a + b*A + c*B + d*A*B, and zero the
// global logit accumulator (consumed by chain_kernel's atomics).
// ---------------------------------------------------------------------------
__global__ void precompute_kernel(const float* __restrict__ c0,
                                  const float* __restrict__ w0,
                                  const float* __restrict__ c1,
                                  const float* __restrict__ w1,
                                  const float* __restrict__ c2,
                                  const float* __restrict__ w2,
                                  float* __restrict__ ws, int nz4) {
  int id = blockIdx.x * blockDim.x + threadIdx.x;
  if (id < 2600) {  // layer-1 col gc=(n,o): softmax over m=32 (stride 325 in src)
    int n = id / 325, o = id - n * 325;
    const float* src = c0 + n * (32 * 325) + o;
    float v[32]; float mx = -3.4e38f;
#pragma unroll
    for (int m = 0; m < 32; ++m) { v[m] = src[m * 325]; mx = fmaxf(mx, v[m]); }
    float ssum = 0.f;
#pragma unroll
    for (int m = 0; m < 32; ++m) { v[m] = __expf(v[m] - mx); ssum += v[m]; }
    float inv = 1.f / ssum;
    float* dst = ws + W0T_OFF + (size_t)id * 32;
#pragma unroll
    for (int m = 0; m < 32; ++m) dst[m] = v[m] * inv;
    return;
  }
  id -= 2600;
  if (id < 5200) {  // layer-2/3 col (k,o): softmax over m=26, pad stride 28
    const float* src0 = (id < 2600) ? c1 : c2;
    float* dst0 = ws + ((id < 2600) ? W1T_OFF : W2T_OFF);
    int col = (id < 2600) ? id : id - 2600;
    int k = col / 52, o = col - k * 52;
    const float* src = src0 + k * (26 * 52) + o;
    float v[26]; float mx = -3.4e38f;
#pragma unroll
    for (int m = 0; m < 26; ++m) { v[m] = src[m * 52]; mx = fmaxf(mx, v[m]); }
    float ssum = 0.f;
#pragma unroll
    for (int m = 0; m < 26; ++m) { v[m] = __expf(v[m] - mx); ssum += v[m]; }
    float inv = 1.f / ssum;
    float* dst = dst0 + (size_t)(k * 52 + o) * 28;
#pragma unroll
    for (int m = 0; m < 26; ++m) dst[m] = v[m] * inv;
    dst[26] = 0.f; dst[27] = 0.f;
    return;
  }
  id -= 5200;
  if (id < 3900) {  // gate coefficients
    int layer = id / 1300, g = id - layer * 1300;
    const float* w = (layer == 0) ? w0 : ((layer == 1) ? w1 : w2);
    float v[16]; float mx = -3.4e38f;
#pragma unroll
    for (int k = 0; k < 16; ++k) { v[k] = w[k * 1300 + g]; mx = fmaxf(mx, v[k]); }
    float ssum = 0.f;
#pragma unroll
    for (int k = 0; k < 16; ++k) { v[k] = __expf(v[k] - mx); ssum += v[k]; }
    float inv = 1.f / ssum;
#pragma unroll
    for (int k = 0; k < 16; ++k) v[k] *= inv;
    float alpha = v[8] + v[9] + v[10] + v[11] + v[12] + v[13] + v[14] + v[15];
    float beta  = v[2] + v[3] + v[6] + v[7] - v[8] - v[9] - v[12] - v[13];
    float gamma = v[4] + v[5] + v[6] + v[7] - v[8] - v[9] - v[10] - v[11];
    float delta = v[1] - v[2] - v[4] - 2.f * v[6] - v[7] + v[8] + 2.f * v[9]
                + v[11] + v[13] - v[14];
    reinterpret_cast<float4*>(ws + CF_OFF)[id] =
        make_float4(alpha, beta, gamma, delta);
    return;
  }
  id -= 3900;
  if (id < nz4) {  // zero logits
    reinterpret_cast<float4*>(ws + LG_OFF)[id] = make_float4(0.f, 0.f, 0.f, 0.f);
  }
}

__device__ __forceinline__ float gate4(float4 cv, float a0, float a1) {
  return fmaf(cv.w, a0 * a1, fmaf(cv.z, a1, fmaf(cv.y, a0, cv.x)));
}
__device__ __forceinline__ float4 vload4(const float* p) {
  return *reinterpret_cast<const float4*>(p);
}
__device__ __forceinline__ float f4c(const float4& v, int c) {
  return c == 0 ? v.x : (c == 1 ? v.y : (c == 2 ? v.z : v.w));
}

// 64 consecutive LDS floats = weight cols (2P,2P+1); consume immediately
__device__ __forceinline__ void dotp32(const float* wp, const float* inp,
                                       float& a0, float& a1) {
#pragma unroll
  for (int t = 0; t < 8; ++t) {
    float4 wA = vload4(wp + 4 * t);
    float4 wB = vload4(wp + 32 + 4 * t);
    a0 = fmaf(inp[4 * t + 0], wA.x, a0);
    a0 = fmaf(inp[4 * t + 1], wA.y, a0);
    a0 = fmaf(inp[4 * t + 2], wA.z, a0);
    a0 = fmaf(inp[4 * t + 3], wA.w, a0);
    a1 = fmaf(inp[4 * t + 0], wB.x, a1);
    a1 = fmaf(inp[4 * t + 1], wB.y, a1);
    a1 = fmaf(inp[4 * t + 2], wB.z, a1);
    a1 = fmaf(inp[4 * t + 3], wB.w, a1);
  }
}
// two 28-float LDS strips (26 used) = weight cols (2q,2q+1)
__device__ __forceinline__ void dotp26(const float* wp, const float* h,
                                       float& a0, float& a1) {
#pragma unroll
  for (int t = 0; t < 7; ++t) {
    float4 wA = vload4(wp + 4 * t);
    float4 wB = vload4(wp + 28 + 4 * t);
#pragma unroll
    for (int c = 0; c < 4; ++c) {
      int j = 4 * t + c;
      if (j < 26) {
        a0 = fmaf(h[j], f4c(wA, c), a0);
        a1 = fmaf(h[j], f4c(wB, c), a1);
      }
    }
  }
}

// ---------------------------------------------------------------------------
// Chain kernel: WG = 8 waves x 64 samples = 512-sample tile; all waves run
// the SAME 2 chains (group g -> chains 2g,2g+1) on their own samples.
// Weights+coeffs for the 2 chains staged into LDS once (39 KB, 1 barrier),
// then streamed via uniform-address ds_read_b128 (counted lgkmcnt ->
// pipelinable, unlike s_load). x read per-lane from global (L3-resident)
// into inp[32] per block-phase. Logits: per-lane global atomicAdd.
// Grid = (B/512) * 25 = 800 WGs (~3/CU at VGPR cap 85, LDS 39 KB).
// ---------------------------------------------------------------------------
static constexpr int LW0_F = 104 * 32;   // 3328
static constexpr int LW1_F = 2 * 52 * 28;  // 2912
static constexpr int LW2_F = 2 * 52 * 28;  // 2912
static constexpr int LCF_4 = 2 * 3 * 26;   // 156 float4

__global__ __launch_bounds__(NT, 6) void chain_kernel(
    const float* __restrict__ x, const float* __restrict__ ws,
    float* __restrict__ lgout, int B) {
  extern __shared__ float smem[];
  float* lw0 = smem;                       // [104][32]
  float* lw1 = smem + LW0_F;               // [2][52][28]
  float* lw2 = lw1 + LW1_F;                // [2][52][28]
  float4* lcf = reinterpret_cast<float4*>(lw2 + LW2_F);  // [2][3][26]

  const int tid = threadIdx.x;
  const int bid = blockIdx.x;
  const int g = bid % 25;                  // chains 2g, 2g+1
  const int tile = bid / 25;
  const int K0 = 2 * g;
  const int s0 = tile * 512;

  // ---- stage weights + coeffs into LDS (coalesced float4 copies) ----
  {
    const float4* s4 = reinterpret_cast<const float4*>(ws + W0T_OFF) +
                       (size_t)(52 * K0) * 8;
    float4* d4 = reinterpret_cast<float4*>(lw0);
    for (int i = tid; i < 832; i += NT) d4[i] = s4[i];
  }
  {
    const float4* s4 = reinterpret_cast<const float4*>(ws + W1T_OFF) +
                       (size_t)K0 * 52 * 7;
    float4* d4 = reinterpret_cast<float4*>(lw1);
    for (int i = tid; i < 728; i += NT) d4[i] = s4[i];
  }
  {
    const float4* s4 = reinterpret_cast<const float4*>(ws + W2T_OFF) +
                       (size_t)K0 * 52 * 7;
    float4* d4 = reinterpret_cast<float4*>(lw2);
    for (int i = tid; i < 728; i += NT) d4[i] = s4[i];
  }
  {
    const float4* cfg = reinterpret_cast<const float4*>(ws + CF_OFF);
    for (int i = tid; i < LCF_4; i += NT) {
      int kc = i / 78, r = i - kc * 78;
      int L = r / 26, q = r - L * 26;
      lcf[i] = cfg[L * 1300 + (K0 + kc) * 26 + q];
    }
  }
  __syncthreads();

  const int lane = tid & 63;
  const int wv = tid >> 6;
  const int s = s0 + wv * 64 + lane;
  const bool valid = (s < B);
  const int sc = valid ? s : (B - 1);
  const float* xs = x + (size_t)sc * 256;

#pragma unroll 1
  for (int kc = 0; kc < 2; ++kc) {
    const int K = K0 + kc;
    const int cs = 52 * K;
    const int nlo = cs / 325;
    const int nhi = (cs + 51) / 325;
    const int split = (nhi > nlo) ? (325 * nhi - cs) : 52;
    const int t1 = split >> 1;
    const int odd = split & 1;
    const float* lw0k = lw0 + (52 * kc) * 32;
    const float4* cf0 = lcf + kc * 78;
    const float4* cf1 = cf0 + 26;
    const float4* cf2 = cf0 + 52;

    float h[26];
    float inp[32];
#pragma unroll
    for (int t = 0; t < 8; ++t) {
      float4 v = vload4(xs + nlo * 32 + 4 * t);
      inp[4 * t] = v.x; inp[4 * t + 1] = v.y;
      inp[4 * t + 2] = v.z; inp[4 * t + 3] = v.w;
    }

    // ---- layer 1, phase A (block nlo) ----
#pragma unroll
    for (int P = 0; P < 26; ++P) {
      if (P < t1) {
        float a0 = 0.f, a1 = 0.f;
        dotp32(lw0k + 2 * P * 32, inp, a0, a1);
        h[P] = gate4(cf0[P], a0, a1);
      }
    }
    // ---- straddle + phase B (block nhi) ----
    if (nhi > nlo) {
      float a0s = 0.f, a1s = 0.f, gs = 0.f;
      if (odd) {
        const float* wp = lw0k + 2 * t1 * 32;
#pragma unroll
        for (int t = 0; t < 8; ++t) {
          float4 w4 = vload4(wp + 4 * t);
          a0s = fmaf(inp[4 * t + 0], w4.x, a0s);
          a0s = fmaf(inp[4 * t + 1], w4.y, a0s);
          a0s = fmaf(inp[4 * t + 2], w4.z, a0s);
          a0s = fmaf(inp[4 * t + 3], w4.w, a0s);
        }
      }
#pragma unroll
      for (int t = 0; t < 8; ++t) {
        float4 v = vload4(xs + nhi * 32 + 4 * t);
        inp[4 * t] = v.x; inp[4 * t + 1] = v.y;
        inp[4 * t + 2] = v.z; inp[4 * t + 3] = v.w;
      }
      if (odd) {
        const float* wq = lw0k + (2 * t1 + 1) * 32;
#pragma unroll
        for (int t = 0; t < 8; ++t) {
          float4 w4 = vload4(wq + 4 * t);
          a1s = fmaf(inp[4 * t + 0], w4.x, a1s);
          a1s = fmaf(inp[4 * t + 1], w4.y, a1s);
          a1s = fmaf(inp[4 * t + 2], w4.z, a1s);
          a1s = fmaf(inp[4 * t + 3], w4.w, a1s);
        }
        gs = gate4(cf0[t1], a0s, a1s);  // dynamic LDS index: fine (memory)
      }
#pragma unroll
      for (int P = 0; P < 26; ++P) {
        if (P >= t1 + odd) {
          float a0 = 0.f, a1 = 0.f;
          dotp32(lw0k + 2 * P * 32, inp, a0, a1);
          h[P] = gate4(cf0[P], a0, a1);
        }
      }
      if (odd) {  // static-index select for the register write
#pragma unroll
        for (int P = 0; P < 26; ++P)
          if (P == t1) h[P] = gs;
      }
    }

    // ---- layer 2 ----
    float h2[26];
    {
      const float* lw1k = lw1 + (52 * kc) * 28;
#pragma unroll
      for (int q = 0; q < 26; ++q) {
        float a0 = 0.f, a1 = 0.f;
        dotp26(lw1k + 2 * q * 28, h, a0, a1);
        h2[q] = gate4(cf1[q], a0, a1);
      }
    }

    // ---- layer 3 + chain sum ----
    float psum = 0.f;
    {
      const float* lw2k = lw2 + (52 * kc) * 28;
#pragma unroll 2
      for (int q = 0; q < 26; ++q) {
        float a0 = 0.f, a1 = 0.f;
        dotp26(lw2k + 2 * q * 28, h2, a0, a1);
        psum += gate4(cf2[q], a0, a1);
      }
    }
    if (valid) atomicAdd(&lgout[(size_t)s * 10 + K / 5], psum);
  }
}

// ---------------------------------------------------------------------------
// Finalize: per-sample 10-way softmax.
// ---------------------------------------------------------------------------
__global__ __launch_bounds__(256) void softmax_kernel(
    const float* __restrict__ lgin, float* __restrict__ out, int B) {
  int s = blockIdx.x * 256 + threadIdx.x;
  if (s >= B) return;
  float lg[10];
#pragma unroll
  for (int c = 0; c < 10; ++c) lg[c] = lgin[(size_t)s * 10 + c];
  float mx = lg[0];
#pragma unroll
  for (int c = 1; c < 10; ++c) mx = fmaxf(mx, lg[c]);
  float ssum = 0.f;
#pragma unroll
  for (int c = 0; c < 10; ++c) { lg[c] = __expf(lg[c] - mx); ssum += lg[c]; }
  float inv = 1.f / ssum;
  float* o = out + (size_t)s * 10;
#pragma unroll
  for (int c = 0; c < 10; ++c) o[c] = lg[c] * inv;
}

extern "C" void kernel_launch(void* const* d_in, const int* in_sizes, int n_in,
                              void* d_out, int out_size, void* d_ws, size_t ws_size,
                              hipStream_t stream) {
  const float* x  = (const float*)d_in[0];
  const float* c0 = (const float*)d_in[1];
  const float* w0 = (const float*)d_in[2];
  const float* c1 = (const float*)d_in[3];
  const float* w1 = (const float*)d_in[4];
  const float* c2 = (const float*)d_in[5];
  const float* w2 = (const float*)d_in[6];
  float* out = (float*)d_out;
  float* ws  = (float*)d_ws;
  const int B = in_sizes[0] / 256;

  const int nz4 = (B * 10 + 3) / 4;
  const int npre = 11700 + nz4;
  precompute_kernel<<<(npre + 255) / 256, 256, 0, stream>>>(
      c0, w0, c1, w1, c2, w2, ws, nz4);

  const size_t smem_bytes =
      (size_t)(LW0_F + LW1_F + LW2_F) * sizeof(float) + LCF_4 * sizeof(float4);
  hipFuncSetAttribute(reinterpret_cast<const void*>(chain_kernel),
                      hipFuncAttributeMaxDynamicSharedMemorySize, (int)smem_bytes);
  const int nblk = (B + 511) / 512;
  chain_kernel<<<nblk * 25, NT, smem_bytes, stream>>>(x, ws, ws + LG_OFF, B);
  softmax_kernel<<<(B + 255) / 256, 256, 0, stream>>>(ws + LG_OFF, out, B);
}